// Round 4
// baseline (93.757 us; speedup 1.0000x reference)
//
#include <hip/hip_runtime.h>
#include <hip/hip_bf16.h>

// Problem: N=64, K=512, D=256. Reference reduces to out = relu(x @ W^T + b):
// softmax over j sums to 1 and einsum 'nkj,nkd->nkd' multiplies h by that sum.
// [32768,256] x [256,256]^T GEMM + bias + ReLU. Memory-bound (~67 MB HBM,
// floor ~10.6us kernel; headline carries ~75us of harness fill overhead).
//
// R1..R6: register-B (42us) -> LDS W-slice (35us) -> coalesced staging
// (29us) -> persistent full-W LDS, x read once (~17us) -> lgkm-only barriers
// + deep prefetch (R6, headline 92.2).
// R8: B in regs via SCATTERED global reads (4x L2 amplification) — 96.1. Bad.
// R9: cooperative W stage -> LDS -> per-wave register-B readback; W buffer
//     reused as lx ping-pong; 1 lgkm-only barrier/tile. Headline 89.9. Good.
// R10 (this round): kill the prologue cross-wave coupling. Each wave stages
//     ITS OWN 32-row W strip (one row per wave-load: 64 lanes x float4 = 1 KB
//     = exactly one W row, fully coalesced), writes to its private LDS strip,
//     readback with wave-local lgkmcnt(0) only. No barrier in the W path at
//     all: waves pipeline through the prologue independently. Barriers:
//     readback-done (before strip reuse) + lx0-ready + 3 loop = 5 total
//     (R9 had 6, and its first barrier serialized the slowest wave's stage).
// Predicted: headline ~88-89; FETCH/WRITE unchanged; conflicts ~0.
// If neutral: prologue is L2-BW-bound (structural ~2us head) -> near-roofline.

#define DD 256          // feature dim
#define M_TOTAL 32768   // N*K rows
#define LWS 264         // LDS row stride in shorts (528 B): measured 0 conflicts

typedef short bf16x8 __attribute__((ext_vector_type(8)));
typedef float floatx16 __attribute__((ext_vector_type(16)));

// Barrier with LDS-only drain: does NOT wait vmcnt, so global prefetch
// loads and nontemporal stores stay in flight across it.
#define BAR() asm volatile("s_waitcnt lgkmcnt(0)\n\ts_barrier" ::: "memory")
// Wave-local LDS drain (no barrier): orders this wave's ds_writes before
// its own ds_reads of the same region.
#define WAVE_FENCE() asm volatile("s_waitcnt lgkmcnt(0)" ::: "memory")

// Pack 8 fp32 -> 8 bf16 (packed cvt, RNE).
__device__ inline bf16x8 pack8(float4 p0, float4 p1) {
    __hip_bfloat162 q0 = __float22bfloat162_rn(make_float2(p0.x, p0.y));
    __hip_bfloat162 q1 = __float22bfloat162_rn(make_float2(p0.z, p0.w));
    __hip_bfloat162 q2 = __float22bfloat162_rn(make_float2(p1.x, p1.y));
    __hip_bfloat162 q3 = __float22bfloat162_rn(make_float2(p1.z, p1.w));
    union { bf16x8 v; unsigned u[4]; } r;
    union { __hip_bfloat162 h; unsigned u; } c;
    c.h = q0; r.u[0] = c.u;
    c.h = q1; r.u[1] = c.u;
    c.h = q2; r.u[2] = c.u;
    c.h = q3; r.u[3] = c.u;
    return r.v;
}

// Pack 4 fp32 -> 4 bf16 (8 B).
__device__ inline uint2 pack4(float4 t) {
    union { __hip_bfloat162 h; unsigned u; } c0, c1;
    c0.h = __float22bfloat162_rn(make_float2(t.x, t.y));
    c1.h = __float22bfloat162_rn(make_float2(t.z, t.w));
    return make_uint2(c0.u, c1.u);
}

// Each thread's share of one 32-row x tile: rows r0 and r0+16, 8 floats at c0.
__device__ inline void load_tile(const float* __restrict__ x, int m0,
                                 int r0, int c0, float4 P[4]) {
    const float* s0 = x + (m0 + r0) * DD + c0;
    const float* s1 = x + (m0 + 16 + r0) * DD + c0;
    P[0] = *(const float4*)(s0);
    P[1] = *(const float4*)(s0 + 4);
    P[2] = *(const float4*)(s1);
    P[3] = *(const float4*)(s1 + 4);
}

__device__ inline void write_lx(unsigned short* lx, int r0, int c0,
                                const float4 P[4]) {
    *(bf16x8*)(lx + r0 * LWS + c0)        = pack8(P[0], P[1]);
    *(bf16x8*)(lx + (16 + r0) * LWS + c0) = pack8(P[2], P[3]);
}

// A from LDS, B from registers (wave-private W strip).
__device__ inline void compute_tile(const unsigned short* ap,
                                    const bf16x8 (&B)[16], floatx16& acc) {
#pragma unroll
    for (int i = 0; i < 16; ++i) acc[i] = 0.f;
#pragma unroll
    for (int s = 0; s < 16; ++s) {
        bf16x8 af = *(const bf16x8*)(ap + s * 16);
        acc = __builtin_amdgcn_mfma_f32_32x32x16_bf16(af, B[s], acc, 0, 0, 0);
    }
}

// C/D layout: col = lane&31, row = (reg&3) + 8*(reg>>2) + 4*(lane>>5)
__device__ inline void store_tile(float* ob, int m0, int lh, float bias,
                                  const floatx16& acc) {
#pragma unroll
    for (int r = 0; r < 16; ++r) {
        const int m = m0 + (r & 3) + 8 * (r >> 2) + 4 * lh;
        float v = acc[r] + bias;
        v = v > 0.f ? v : 0.f;
        __builtin_nontemporal_store(v, ob + m * DD);
    }
}

// 512 thr = 8 waves; wave w owns e-strip [w*32, w*32+32). Block owns 128
// contiguous m-rows = 4 tiles of 32. Grid = 256 (1 block/CU).
__global__ void __launch_bounds__(512, 1)
fcgat_gemm(const float* __restrict__ x, const float* __restrict__ W,
           const float* __restrict__ Wbias, float* __restrict__ out) {
    // 132 KB: 8 wave-private W strips (32 rows each) for the prologue;
    // strips of waves 0/1 (rows 0..63) reused as the lx ping-pong after.
    __shared__ __align__(16) unsigned short lw[256 * LWS];

    const int tid   = threadIdx.x;        // 0..511
    const int r0    = tid >> 5;           // 0..15 (x staging row base)
    const int c0    = (tid & 31) * 8;     // x staging col (floats/shorts)
    const int mbase = blockIdx.x * 128;

    const int lane = tid & 63;
    const int wave = tid >> 6;            // 0..7 -> e-strip
    const int ln   = lane & 31;
    const int lh   = lane >> 5;           // k-half (0/1)

    unsigned short* lx0 = lw;             // wave0 strip region
    unsigned short* lx1 = lw + 32 * LWS;  // wave1 strip region

    // ---- issue tiles 0..2 x-prefetch FIRST (HBM stream starts now, stays
    // in flight through the whole W prologue) -------------------------------
    float4 Pa[4], Pb[4], Pc[4];
    load_tile(x, mbase + 0,  r0, c0, Pa);
    load_tile(x, mbase + 32, r0, c0, Pb);
    load_tile(x, mbase + 64, r0, c0, Pc);

    // ---- per-wave W strip stage: rows [wave*32, +32), ONE ROW PER WAVE-LOAD
    // (lane l -> cols [4l, 4l+4): 64 lanes x 16 B = the full 1 KB row).
    // Writes only this wave's private strip: no cross-wave barrier needed.
    {
        unsigned short* wst = lw + wave * 32 * LWS;
        const float* wsrc = W + (wave * 32) * DD + lane * 4;
#pragma unroll
        for (int rc = 0; rc < 32; rc += 16) {
            float4 t[16];
#pragma unroll
            for (int r = 0; r < 16; ++r)
                t[r] = *(const float4*)(wsrc + (rc + r) * DD);
#pragma unroll
            for (int r = 0; r < 16; ++r)
                *(uint2*)(wst + (rc + r) * LWS + lane * 4) = pack4(t[r]);
        }
    }
    WAVE_FENCE();                         // this wave's strip writes retired

    // ---- readback into registers (0-conflict ds_read_b128 layout) ---------
    bf16x8 B[16];
    {
        const unsigned short* bp = lw + (wave * 32 + ln) * LWS + lh * 8;
#pragma unroll
        for (int s = 0; s < 16; ++s) B[s] = *(const bf16x8*)(bp + s * 16);
    }
    BAR();                                // all readbacks done; strips reusable

    const unsigned short* ap0 = lx0 + ln * LWS + lh * 8;
    const unsigned short* ap1 = lx1 + ln * LWS + lh * 8;
    const float bias = Wbias[wave * 32 + ln];
    float* ob = out + wave * 32 + ln;

    write_lx(lx0, r0, c0, Pa);            // waits only Pa's loads (fine vmcnt)
    BAR();                                // lx0 ready

    floatx16 acc;

    // ---- tile 0 ----
    load_tile(x, mbase + 96, r0, c0, Pa); // t3 into freed regs
    compute_tile(ap0, B, acc);
    write_lx(lx1, r0, c0, Pb);            // stage t1 (lx1 has no reader yet)
    store_tile(ob, mbase + 0, lh, bias, acc);
    BAR();                                // lx1 ready; lx0 free

    // ---- tile 1 ----
    compute_tile(ap1, B, acc);
    write_lx(lx0, r0, c0, Pc);            // stage t2
    store_tile(ob, mbase + 32, lh, bias, acc);
    BAR();                                // lx0 ready; lx1 free

    // ---- tile 2 ----
    compute_tile(ap0, B, acc);
    write_lx(lx1, r0, c0, Pa);            // stage t3
    store_tile(ob, mbase + 64, lh, bias, acc);
    BAR();                                // lx1 ready

    // ---- tile 3 ----
    compute_tile(ap1, B, acc);
    store_tile(ob, mbase + 96, lh, bias, acc);
}

extern "C" void kernel_launch(void* const* d_in, const int* in_sizes, int n_in,
                              void* d_out, int out_size, void* d_ws, size_t ws_size,
                              hipStream_t stream) {
    const float* x    = (const float*)d_in[0];  // [64,512,256]
    const float* W_w  = (const float*)d_in[1];  // [256,256]
    const float* W_b  = (const float*)d_in[2];  // [256]
    // d_in[3] = att_w, d_in[4] = att_b — provably unused (softmax sums to 1)
    float* out = (float*)d_out;                 // [64,512,256] fp32

    fcgat_gemm<<<M_TOTAL / 128, 512, 0, stream>>>(x, W_w, W_b, out);
}

// Round 7
// 90.495 us; speedup vs baseline: 1.0360x; 1.0360x over previous
//
#include <hip/hip_runtime.h>
#include <hip/hip_bf16.h>

// Problem: N=64, K=512, D=256. Reference reduces to out = relu(x @ W^T + b):
// softmax over j sums to 1 and einsum 'nkj,nkd->nkd' multiplies h by that sum.
// [32768,256] x [256,256]^T GEMM + bias + ReLU. Memory-bound (~67 MB HBM,
// floor ~10.6us kernel; headline carries ~75us of harness fill overhead).
//
// R6: persistent full-W LDS + lgkm-only barriers, x once — headline 92.2.
// R8: B in regs via scattered global reads — 96.1 (bad).
// R9: cooperative W stage -> per-wave register-B readback; W buffer reused as
//     lx ping-pong; 1 lgkm-only barrier/tile — 89.9 (best).
// R10: per-wave W stage, t[16] batch (+64 VGPR, likely spill) — 93.8.
// R11: FAILED correctness. LWW=136 gave each W row 136 shorts for 256 bf16
//      values -> rows overwrote each other (absmax 45.75). Lesson: R9's lw
//      was already bf16-minimal; de-aliased W (132K) + ping-pong lx (33K)
//      exceeds 160 KB. The readback barrier is capacity-mandatory.
// R12: R9 EXACTLY (aliased lx, readback barrier restored) plus the one valid
//      R11 piece: 4-deep x prefetch (Pa..Pd in prologue; whole 64 KB x
//      stream in flight before W staging; tile0 body has no loads).
// R13 (this round): resubmit R12 unchanged — previous bench was an MI355X
//      container/broker failure (never measured). Prediction stands:
//      passes (absmax ~0.03); headline 89-90. If within noise of R9's 89.9
//      -> residual is structural W L2 head + HBM: declare roofline.

#define DD 256          // feature dim
#define M_TOTAL 32768   // N*K rows
#define LWS 264         // LDS row stride in shorts (528 B): measured 0 conflicts

typedef short bf16x8 __attribute__((ext_vector_type(8)));
typedef float floatx16 __attribute__((ext_vector_type(16)));

// Barrier with LDS-only drain: does NOT wait vmcnt, so global prefetch
// loads and nontemporal stores stay in flight across it.
#define BAR() asm volatile("s_waitcnt lgkmcnt(0)\n\ts_barrier" ::: "memory")

// Pack 8 fp32 -> 8 bf16 (packed cvt, RNE).
__device__ inline bf16x8 pack8(float4 p0, float4 p1) {
    __hip_bfloat162 q0 = __float22bfloat162_rn(make_float2(p0.x, p0.y));
    __hip_bfloat162 q1 = __float22bfloat162_rn(make_float2(p0.z, p0.w));
    __hip_bfloat162 q2 = __float22bfloat162_rn(make_float2(p1.x, p1.y));
    __hip_bfloat162 q3 = __float22bfloat162_rn(make_float2(p1.z, p1.w));
    union { bf16x8 v; unsigned u[4]; } r;
    union { __hip_bfloat162 h; unsigned u; } c;
    c.h = q0; r.u[0] = c.u;
    c.h = q1; r.u[1] = c.u;
    c.h = q2; r.u[2] = c.u;
    c.h = q3; r.u[3] = c.u;
    return r.v;
}

// Each thread's share of one 32-row x tile: rows r0 and r0+16, 8 floats at c0.
__device__ inline void load_tile(const float* __restrict__ x, int m0,
                                 int r0, int c0, float4 P[4]) {
    const float* s0 = x + (m0 + r0) * DD + c0;
    const float* s1 = x + (m0 + 16 + r0) * DD + c0;
    P[0] = *(const float4*)(s0);
    P[1] = *(const float4*)(s0 + 4);
    P[2] = *(const float4*)(s1);
    P[3] = *(const float4*)(s1 + 4);
}

__device__ inline void write_lx(unsigned short* lx, int r0, int c0,
                                const float4 P[4]) {
    *(bf16x8*)(lx + r0 * LWS + c0)        = pack8(P[0], P[1]);
    *(bf16x8*)(lx + (16 + r0) * LWS + c0) = pack8(P[2], P[3]);
}

// A from LDS, B from registers (wave-private W strip).
__device__ inline void compute_tile(const unsigned short* ap,
                                    const bf16x8 (&B)[16], floatx16& acc) {
#pragma unroll
    for (int i = 0; i < 16; ++i) acc[i] = 0.f;
#pragma unroll
    for (int s = 0; s < 16; ++s) {
        bf16x8 af = *(const bf16x8*)(ap + s * 16);
        acc = __builtin_amdgcn_mfma_f32_32x32x16_bf16(af, B[s], acc, 0, 0, 0);
    }
}

// C/D layout: col = lane&31, row = (reg&3) + 8*(reg>>2) + 4*(lane>>5)
__device__ inline void store_tile(float* ob, int m0, int lh, float bias,
                                  const floatx16& acc) {
#pragma unroll
    for (int r = 0; r < 16; ++r) {
        const int m = m0 + (r & 3) + 8 * (r >> 2) + 4 * lh;
        float v = acc[r] + bias;
        v = v > 0.f ? v : 0.f;
        __builtin_nontemporal_store(v, ob + m * DD);
    }
}

// 512 thr = 8 waves; wave w owns e-strip [w*32, w*32+32). Block owns 128
// contiguous m-rows = 4 tiles of 32. Grid = 256 (1 block/CU).
__global__ void __launch_bounds__(512, 1)
fcgat_gemm(const float* __restrict__ x, const float* __restrict__ W,
           const float* __restrict__ Wbias, float* __restrict__ out) {
    // 132 KB: W staging for the prologue; first 33 KB reused as lx ping-pong
    // for the main loop (W-LDS dead once B[] is in registers — gated by the
    // readback barrier, which is capacity-mandatory per R11's failure).
    __shared__ __align__(16) unsigned short lw[256 * LWS];

    const int tid   = threadIdx.x;        // 0..511
    const int r0    = tid >> 5;           // 0..15 (staging row base)
    const int c0    = (tid & 31) * 8;     // staging col (floats/shorts)
    const int mbase = blockIdx.x * 128;

    const int lane = tid & 63;
    const int wave = tid >> 6;            // 0..7 -> e-strip
    const int ln   = lane & 31;
    const int lh   = lane >> 5;           // k-half (0/1)

    unsigned short* lx0 = lw;
    unsigned short* lx1 = lw + 32 * LWS;

    // ---- issue ALL FOUR x tiles' prefetch first (64 KB/block in flight
    // through the whole W prologue; HBM stream starts immediately) ----------
    float4 Pa[4], Pb[4], Pc[4], Pd[4];
    load_tile(x, mbase + 0,  r0, c0, Pa);
    load_tile(x, mbase + 32, r0, c0, Pb);
    load_tile(x, mbase + 64, r0, c0, Pc);
    load_tile(x, mbase + 96, r0, c0, Pd);

    // ---- stage full W fp32 -> bf16 -> LDS, COALESCED (32 lanes = 1 row) ---
#pragma unroll
    for (int k = 0; k < 16; ++k) {
        const int r = r0 + 16 * k;        // 0..255
        const float* ws = W + r * DD + c0;
        float4 a0 = *(const float4*)(ws);
        float4 a1 = *(const float4*)(ws + 4);
        *(bf16x8*)(lw + r * LWS + c0) = pack8(a0, a1);
    }
    BAR();                                // W visible to all waves

    // ---- each wave pulls ITS OWN 32-row W strip into registers ------------
    // (ds_read_b128 at the measured-0-conflict LWS=264 layout)
    bf16x8 B[16];
    {
        const unsigned short* bp = lw + (wave * 32 + ln) * LWS + lh * 8;
#pragma unroll
        for (int s = 0; s < 16; ++s) B[s] = *(const bf16x8*)(bp + s * 16);
    }
    BAR();                                // all readbacks done; strips reusable

    const unsigned short* ap0 = lx0 + ln * LWS + lh * 8;
    const unsigned short* ap1 = lx1 + ln * LWS + lh * 8;
    const float bias = Wbias[wave * 32 + ln];
    float* ob = out + wave * 32 + ln;

    write_lx(lx0, r0, c0, Pa);            // Pa long since arrived
    BAR();                                // lx0 ready

    floatx16 acc;

    // ---- tile 0 ----
    compute_tile(ap0, B, acc);
    write_lx(lx1, r0, c0, Pb);            // stage t1 (lx1 has no reader yet)
    store_tile(ob, mbase + 0, lh, bias, acc);
    BAR();                                // lx1 ready; lx0 free

    // ---- tile 1 ----
    compute_tile(ap1, B, acc);
    write_lx(lx0, r0, c0, Pc);            // stage t2
    store_tile(ob, mbase + 32, lh, bias, acc);
    BAR();                                // lx0 ready; lx1 free

    // ---- tile 2 ----
    compute_tile(ap0, B, acc);
    write_lx(lx1, r0, c0, Pd);            // stage t3
    store_tile(ob, mbase + 64, lh, bias, acc);
    BAR();                                // lx1 ready

    // ---- tile 3 ----
    compute_tile(ap1, B, acc);
    store_tile(ob, mbase + 96, lh, bias, acc);
}

extern "C" void kernel_launch(void* const* d_in, const int* in_sizes, int n_in,
                              void* d_out, int out_size, void* d_ws, size_t ws_size,
                              hipStream_t stream) {
    const float* x    = (const float*)d_in[0];  // [64,512,256]
    const float* W_w  = (const float*)d_in[1];  // [256,256]
    const float* W_b  = (const float*)d_in[2];  // [256]
    // d_in[3] = att_w, d_in[4] = att_b — provably unused (softmax sums to 1)
    float* out = (float*)d_out;                 // [64,512,256] fp32

    fcgat_gemm<<<M_TOTAL / 128, 512, 0, stream>>>(x, W_w, W_b, out);
}